// Round 2
// baseline (411.084 us; speedup 1.0000x reference)
//
#include <hip/hip_runtime.h>
#include <math.h>

// One thread per row (B = 1e6, 24 f32 in, 48+32 f32 out).
// Memory-bound: 416 B/row -> ~66 us floor at 6.3 TB/s.
//
// Correctness strategy: replicate numpy float32 arithmetic bit-exactly on
// every path feeding a decision (nearest-neighbor argmin, std clamp):
//  - no FMA contraction (pragma below; default -ffp-contract=fast honors it)
//  - compare sqrt'd distances like the reference (not d^2), incl. +100 diag
//  - IEEE division (plain '/'), not reciprocal-multiply
//  - sequential left-associated 4-element reductions (numpy umr_sum order)
//  - numpy std ddof=1: re-center `centered` by its own mean before squaring

__global__ __launch_bounds__(256) void speaker_kernel(
    const float* __restrict__ in, float* __restrict__ out, int B) {
#pragma clang fp contract(off)
  int idx = blockIdx.x * blockDim.x + threadIdx.x;
  if (idx >= B) return;

  // ---- load 24 floats as 6 float4 (row stride 96 B is 16B-aligned) ----
  const float4* in4 = (const float4*)in + (size_t)idx * 6;
  float r[24];
  float4 tmp[6];
#pragma unroll
  for (int i = 0; i < 6; ++i) tmp[i] = in4[i];
#pragma unroll
  for (int i = 0; i < 6; ++i) {
    r[4 * i + 0] = tmp[i].x;
    r[4 * i + 1] = tmp[i].y;
    r[4 * i + 2] = tmp[i].z;
    r[4 * i + 3] = tmp[i].w;
  }

  float px[4], py[4], vx[4], vy[4], q[4];
#pragma unroll
  for (int i = 0; i < 4; ++i) {
    px[i] = r[5 * i + 0];
    py[i] = r[5 * i + 1];
    vx[i] = r[5 * i + 2];
    vy[i] = r[5 * i + 3];
    q[i]  = r[5 * i + 4];
  }
  float gx = r[20], gy = r[21], gq = r[22], gm = r[23];

  // goal_pos = gp / max(||gp||, 1e-12)  (IEEE div, no contraction)
  float gn  = sqrtf(gx * gx + gy * gy);
  float den = fmaxf(gn, 1e-12f);
  float gpx = gx / den;
  float gpy = gy / den;

  // jnp.sign(goal_motion)
  float sgn = (gm > 0.0f) ? 1.0f : ((gm < 0.0f) ? -1.0f : 0.0f);

  // anchor = positions.mean(axis=1): sequential sum, then /4
  float ax = (((px[0] + px[1]) + px[2]) + px[3]) / 4.0f;
  float ay = (((py[0] + py[1]) + py[2]) + py[3]) / 4.0f;

  float s[4];
#pragma unroll
  for (int i = 0; i < 4; ++i) {
    // masked[i][j] = sqrt(dx^2+dy^2) + (i==j ? 100 : 0); argmin, first occ.
    float best = 3.0e38f;
    float vnx = 0.0f, vny = 0.0f;
#pragma unroll
    for (int j = 0; j < 4; ++j) {
      float dj;
      if (j == i) {
        dj = 100.0f;  // sqrt(0) + 100
      } else {
        float dx = px[i] - px[j];
        float dy = py[i] - py[j];
        dj = sqrtf(dx * dx + dy * dy);
      }
      if (dj < best) { best = dj; vnx = vx[j]; vny = vy[j]; }
    }
    float pos_score = (px[i] * gpx) + (py[i] * gpy);
    float q_score   = q[i] * gq;
    float va        = ((vx[i] * vnx) + (vy[i] * vny)) * gm;
    float dxa = px[i] - ax;
    float dya = py[i] - ay;
    float rel = (-sqrtf(dxa * dxa + dya * dya)) * sgn;
    float t0 = 0.25f * pos_score;
    float t1 = 1.15f * q_score;
    float t2 = 0.9f * va;
    float t3 = 0.15f * rel;
    s[i] = ((t0 + t1) + t2) + t3;
  }

  // mean / centered
  float mean = (((s[0] + s[1]) + s[2]) + s[3]) / 4.0f;
  float c0 = s[0] - mean, c1 = s[1] - mean, c2 = s[2] - mean, c3 = s[3] - mean;

  // np.std(centered, ddof=1): re-center by mean(centered), then sum sq / 3
  float m2 = (((c0 + c1) + c2) + c3) / 4.0f;
  float x0 = c0 - m2, x1 = c1 - m2, x2 = c2 - m2, x3 = c3 - m2;
  float var = ((((x0 * x0) + (x1 * x1)) + (x2 * x2)) + (x3 * x3)) / 3.0f;
  float std = sqrtf(var);
  float dn  = fmaxf(std, 1e-4f);

  // normalized = centered / dn  (IEEE div), then tanh
  float t0 = tanhf(c0 / dn);
  float t1 = tanhf(c1 / dn);
  float t2 = tanhf(c2 / dn);
  float t3 = tanhf(c3 / dn);
  float t4 = tanhf(gq);
  float t5 = tanhf(gm);

  // 6-value pattern tiled into float4s: period lcm(4,6)=12 -> 3 vectors
  float4 A  = {t0, t1, t2, t3};
  float4 Bv = {t4, t5, t0, t1};
  float4 C  = {t2, t3, t4, t5};

  // comm: 48 floats = (A,Bv,C) x 4
  float4* oc = (float4*)out + (size_t)idx * 12;
#pragma unroll
  for (int k = 0; k < 4; ++k) {
    oc[3 * k + 0] = A;
    oc[3 * k + 1] = Bv;
    oc[3 * k + 2] = C;
  }
  // state: 32 floats = flat[:32] = A,Bv,C,A,Bv,C,A,Bv
  float4* os = (float4*)out + (size_t)B * 12 + (size_t)idx * 8;
  os[0] = A; os[1] = Bv; os[2] = C; os[3] = A;
  os[4] = Bv; os[5] = C; os[6] = A; os[7] = Bv;
}

extern "C" void kernel_launch(void* const* d_in, const int* in_sizes, int n_in,
                              void* d_out, int out_size, void* d_ws, size_t ws_size,
                              hipStream_t stream) {
  const float* in = (const float*)d_in[0];
  float* out = (float*)d_out;
  int B = in_sizes[0] / 24;
  int threads = 256;
  int blocks = (B + threads - 1) / threads;
  speaker_kernel<<<blocks, threads, 0, stream>>>(in, out, B);
}

// Round 3
// 383.475 us; speedup vs baseline: 1.0720x; 1.0720x over previous
//
#include <hip/hip_runtime.h>
#include <math.h>

// One thread per row (B = 1e6, 24 f32 in, 48+32 f32 out).
// Memory-bound: 416 B/row -> ~66 us floor at 6.3 TB/s.
//
// R3 change: outputs staged in LDS then flushed with fully-coalesced wave
// stores (lane i -> consecutive float4). R2's direct stores strided 192 B
// across lanes -> ~64 cache lines per store instruction (~16x issue cost).
//
// Compute path is bit-exact numpy f32 (verified R2, absmax 3.9e-3):
//  - no FMA contraction, sqrt'd distance compare, IEEE div,
//    left-associated reductions, numpy ddof=1 re-centered std.

#define TPB 256

__global__ __launch_bounds__(TPB) void speaker_kernel(
    const float* __restrict__ in, float* __restrict__ out, int B) {
#pragma clang fp contract(off)
  // 3 result float4s per row, padded stride 13 to spread bank groups.
  __shared__ float4 st[TPB * 13];  // 53,248 B -> 3 blocks/CU

  const int t = threadIdx.x;
  const int blockBase = blockIdx.x * TPB;
  const int idx = blockBase + t;

  if (idx < B) {
    // ---- load 24 floats as 6 float4 (row stride 96 B, 16B-aligned) ----
    const float4* in4 = (const float4*)in + (size_t)idx * 6;
    float r[24];
    float4 tmp[6];
#pragma unroll
    for (int i = 0; i < 6; ++i) tmp[i] = in4[i];
#pragma unroll
    for (int i = 0; i < 6; ++i) {
      r[4 * i + 0] = tmp[i].x;
      r[4 * i + 1] = tmp[i].y;
      r[4 * i + 2] = tmp[i].z;
      r[4 * i + 3] = tmp[i].w;
    }

    float px[4], py[4], vx[4], vy[4], q[4];
#pragma unroll
    for (int i = 0; i < 4; ++i) {
      px[i] = r[5 * i + 0];
      py[i] = r[5 * i + 1];
      vx[i] = r[5 * i + 2];
      vy[i] = r[5 * i + 3];
      q[i]  = r[5 * i + 4];
    }
    float gx = r[20], gy = r[21], gq = r[22], gm = r[23];

    // goal_pos = gp / max(||gp||, 1e-12)  (IEEE div, no contraction)
    float gn  = sqrtf(gx * gx + gy * gy);
    float den = fmaxf(gn, 1e-12f);
    float gpx = gx / den;
    float gpy = gy / den;

    // jnp.sign(goal_motion)
    float sgn = (gm > 0.0f) ? 1.0f : ((gm < 0.0f) ? -1.0f : 0.0f);

    // anchor = positions.mean(axis=1): sequential sum, then /4
    float ax = (((px[0] + px[1]) + px[2]) + px[3]) / 4.0f;
    float ay = (((py[0] + py[1]) + py[2]) + py[3]) / 4.0f;

    float s[4];
#pragma unroll
    for (int i = 0; i < 4; ++i) {
      // masked[i][j] = sqrt(dx^2+dy^2) + (i==j ? 100 : 0); argmin, first occ.
      float best = 3.0e38f;
      float vnx = 0.0f, vny = 0.0f;
#pragma unroll
      for (int j = 0; j < 4; ++j) {
        float dj;
        if (j == i) {
          dj = 100.0f;  // sqrt(0) + 100
        } else {
          float dx = px[i] - px[j];
          float dy = py[i] - py[j];
          dj = sqrtf(dx * dx + dy * dy);
        }
        if (dj < best) { best = dj; vnx = vx[j]; vny = vy[j]; }
      }
      float pos_score = (px[i] * gpx) + (py[i] * gpy);
      float q_score   = q[i] * gq;
      float va        = ((vx[i] * vnx) + (vy[i] * vny)) * gm;
      float dxa = px[i] - ax;
      float dya = py[i] - ay;
      float rel = (-sqrtf(dxa * dxa + dya * dya)) * sgn;
      float u0 = 0.25f * pos_score;
      float u1 = 1.15f * q_score;
      float u2 = 0.9f * va;
      float u3 = 0.15f * rel;
      s[i] = ((u0 + u1) + u2) + u3;
    }

    // mean / centered
    float mean = (((s[0] + s[1]) + s[2]) + s[3]) / 4.0f;
    float c0 = s[0] - mean, c1 = s[1] - mean, c2 = s[2] - mean, c3 = s[3] - mean;

    // np.std(centered, ddof=1): re-center by mean(centered), sum sq / 3
    float m2 = (((c0 + c1) + c2) + c3) / 4.0f;
    float x0 = c0 - m2, x1 = c1 - m2, x2 = c2 - m2, x3 = c3 - m2;
    float var = ((((x0 * x0) + (x1 * x1)) + (x2 * x2)) + (x3 * x3)) / 3.0f;
    float std = sqrtf(var);
    float dn  = fmaxf(std, 1e-4f);

    // normalized = centered / dn  (IEEE div), then tanh
    float t0 = tanhf(c0 / dn);
    float t1 = tanhf(c1 / dn);
    float t2 = tanhf(c2 / dn);
    float t3 = tanhf(c3 / dn);
    float t4 = tanhf(gq);
    float t5 = tanhf(gm);

    // 6-value pattern tiled into float4s: period lcm(4,6)=12 -> 3 vectors
    st[t * 13 + 0] = make_float4(t0, t1, t2, t3);           // A
    st[t * 13 + 1] = make_float4(t4, t5, t0, t1);           // Bv
    st[t * 13 + 2] = make_float4(t2, t3, t4, t5);           // C
  }

  __syncthreads();

  // ---- coalesced flush: lane i writes consecutive float4s ----
  // comm: rows of 12 float4s = (A,Bv,C) x 4 ; pattern = (o%12)%3
  {
    float4* oc = (float4*)out + (size_t)blockBase * 12;
#pragma unroll
    for (int k = 0; k < 12; ++k) {
      int o = t + TPB * k;          // float4 index within block's comm region
      int row = o / 12;
      int pat = (o % 12) % 3;
      if (blockBase + row < B) oc[o] = st[row * 13 + pat];
    }
  }
  // state: rows of 8 float4s = A,Bv,C,A,Bv,C,A,Bv ; pattern = (o%8)%3
  {
    float4* os = (float4*)out + (size_t)B * 12 + (size_t)blockBase * 8;
#pragma unroll
    for (int k = 0; k < 8; ++k) {
      int o = t + TPB * k;
      int row = o / 8;
      int pat = (o % 8) % 3;
      if (blockBase + row < B) os[o] = st[row * 13 + pat];
    }
  }
}

extern "C" void kernel_launch(void* const* d_in, const int* in_sizes, int n_in,
                              void* d_out, int out_size, void* d_ws, size_t ws_size,
                              hipStream_t stream) {
  const float* in = (const float*)d_in[0];
  float* out = (float*)d_out;
  int B = in_sizes[0] / 24;
  int blocks = (B + TPB - 1) / TPB;
  speaker_kernel<<<blocks, TPB, 0, stream>>>(in, out, B);
}

// Round 5
// 371.769 us; speedup vs baseline: 1.1057x; 1.0315x over previous
//
#include <hip/hip_runtime.h>
#include <math.h>

// One thread per row (B = 1e6, 24 f32 in, 48+32 f32 out).
// Memory floor: 416 B/row -> ~66-90 us (mixed-stream) at ~6.3 TB/s.
//
// R5 = R4 with the nontemporal builtins fed a native clang vector type
// (HIP float4 is a struct -> rejected by __builtin_nontemporal_*).
//
// R4 rationale:
//  - nontemporal loads/stores: output written once & never re-read; input
//    read once. Streams past L2/L3, avoiding interaction with the 1.25 GB
//    0xAA poison fill preceding every timed launch.
//  - input staged via LDS j-major: all 6 global loads fully lane-contiguous;
//    read-back is the optimal contiguous ds_read_b128 pattern.
//  - LDS 36 KB total (24 in + 12 out) -> 4 blocks/CU.
//
// Compute path is bit-exact numpy f32 (verified R2/R3, absmax 3.9e-3):
//  - no FMA contraction, sqrt'd distance compare, IEEE div,
//    left-associated reductions, numpy ddof=1 re-centered std.

#define TPB 256

typedef float vfloat4 __attribute__((ext_vector_type(4)));

__global__ __launch_bounds__(TPB) void speaker_kernel(
    const float* __restrict__ in, float* __restrict__ out, int B) {
#pragma clang fp contract(off)
  __shared__ vfloat4 ldin[6 * TPB];  // j-major: ldin[j*TPB + row]  24 KB
  __shared__ vfloat4 st[TPB * 3];    // A,Bv,C per row              12 KB

  const int t = threadIdx.x;
  const int blockBase = blockIdx.x * TPB;
  const int rowsInBlock = min(TPB, B - blockBase);
  const int nf4 = rowsInBlock * 6;  // input float4s this block

  // ---- Phase 1: coalesced global -> LDS (lane-contiguous nt loads) ----
  {
    const vfloat4* gin = (const vfloat4*)in + (size_t)blockBase * 6;
#pragma unroll
    for (int k = 0; k < 6; ++k) {
      int o = t + TPB * k;  // f4 index in block's input region
      if (o < nf4) {
        int row = o / 6;
        int j = o - row * 6;
        ldin[j * TPB + row] = __builtin_nontemporal_load(gin + o);
      }
    }
  }
  __syncthreads();

  // ---- Phase 2: per-row compute (bit-exact numpy f32) ----
  if (t < rowsInBlock) {
    float r[24];
#pragma unroll
    for (int j = 0; j < 6; ++j) {
      vfloat4 v = ldin[j * TPB + t];  // contiguous-by-lane b128: optimal
      r[4 * j + 0] = v.x;
      r[4 * j + 1] = v.y;
      r[4 * j + 2] = v.z;
      r[4 * j + 3] = v.w;
    }

    float px[4], py[4], vx[4], vy[4], q[4];
#pragma unroll
    for (int i = 0; i < 4; ++i) {
      px[i] = r[5 * i + 0];
      py[i] = r[5 * i + 1];
      vx[i] = r[5 * i + 2];
      vy[i] = r[5 * i + 3];
      q[i]  = r[5 * i + 4];
    }
    float gx = r[20], gy = r[21], gq = r[22], gm = r[23];

    // goal_pos = gp / max(||gp||, 1e-12)  (IEEE div, no contraction)
    float gn  = sqrtf(gx * gx + gy * gy);
    float den = fmaxf(gn, 1e-12f);
    float gpx = gx / den;
    float gpy = gy / den;

    // jnp.sign(goal_motion)
    float sgn = (gm > 0.0f) ? 1.0f : ((gm < 0.0f) ? -1.0f : 0.0f);

    // anchor = positions.mean(axis=1): sequential sum, then /4
    float ax = (((px[0] + px[1]) + px[2]) + px[3]) / 4.0f;
    float ay = (((py[0] + py[1]) + py[2]) + py[3]) / 4.0f;

    float s[4];
#pragma unroll
    for (int i = 0; i < 4; ++i) {
      // masked[i][j] = sqrt(dx^2+dy^2) + (i==j ? 100 : 0); argmin, first occ.
      float best = 3.0e38f;
      float vnx = 0.0f, vny = 0.0f;
#pragma unroll
      for (int j = 0; j < 4; ++j) {
        float dj;
        if (j == i) {
          dj = 100.0f;  // sqrt(0) + 100
        } else {
          float dx = px[i] - px[j];
          float dy = py[i] - py[j];
          dj = sqrtf(dx * dx + dy * dy);
        }
        if (dj < best) { best = dj; vnx = vx[j]; vny = vy[j]; }
      }
      float pos_score = (px[i] * gpx) + (py[i] * gpy);
      float q_score   = q[i] * gq;
      float va        = ((vx[i] * vnx) + (vy[i] * vny)) * gm;
      float dxa = px[i] - ax;
      float dya = py[i] - ay;
      float rel = (-sqrtf(dxa * dxa + dya * dya)) * sgn;
      float u0 = 0.25f * pos_score;
      float u1 = 1.15f * q_score;
      float u2 = 0.9f * va;
      float u3 = 0.15f * rel;
      s[i] = ((u0 + u1) + u2) + u3;
    }

    // mean / centered
    float mean = (((s[0] + s[1]) + s[2]) + s[3]) / 4.0f;
    float c0 = s[0] - mean, c1 = s[1] - mean, c2 = s[2] - mean, c3 = s[3] - mean;

    // np.std(centered, ddof=1): re-center by mean(centered), sum sq / 3
    float m2 = (((c0 + c1) + c2) + c3) / 4.0f;
    float x0 = c0 - m2, x1 = c1 - m2, x2 = c2 - m2, x3 = c3 - m2;
    float var = ((((x0 * x0) + (x1 * x1)) + (x2 * x2)) + (x3 * x3)) / 3.0f;
    float std = sqrtf(var);
    float dn  = fmaxf(std, 1e-4f);

    // normalized = centered / dn  (IEEE div), then tanh
    float t0 = tanhf(c0 / dn);
    float t1 = tanhf(c1 / dn);
    float t2 = tanhf(c2 / dn);
    float t3 = tanhf(c3 / dn);
    float t4 = tanhf(gq);
    float t5 = tanhf(gm);

    // 6-value pattern tiled into float4s: period lcm(4,6)=12 -> 3 vectors
    vfloat4 A  = {t0, t1, t2, t3};
    vfloat4 Bv = {t4, t5, t0, t1};
    vfloat4 C  = {t2, t3, t4, t5};
    st[t * 3 + 0] = A;
    st[t * 3 + 1] = Bv;
    st[t * 3 + 2] = C;
  }

  __syncthreads();

  // ---- Phase 3: coalesced nontemporal flush ----
  // comm: rows of 12 float4s = (A,Bv,C) x 4 ; pat = (o%12)%3 = o%3
  {
    vfloat4* oc = (vfloat4*)out + (size_t)blockBase * 12;
    const int nc = rowsInBlock * 12;
#pragma unroll
    for (int k = 0; k < 12; ++k) {
      int o = t + TPB * k;
      if (o < nc) {
        int row = o / 12;
        int pat = o % 3;
        __builtin_nontemporal_store(st[row * 3 + pat], oc + o);
      }
    }
  }
  // state: rows of 8 float4s = A,Bv,C,A,Bv,C,A,Bv ; pat = (o%8)%3
  {
    vfloat4* os = (vfloat4*)out + (size_t)B * 12 + (size_t)blockBase * 8;
    const int ns = rowsInBlock * 8;
#pragma unroll
    for (int k = 0; k < 8; ++k) {
      int o = t + TPB * k;
      if (o < ns) {
        int row = o >> 3;
        int pat = (o & 7) % 3;
        __builtin_nontemporal_store(st[row * 3 + pat], os + o);
      }
    }
  }
}

extern "C" void kernel_launch(void* const* d_in, const int* in_sizes, int n_in,
                              void* d_out, int out_size, void* d_ws, size_t ws_size,
                              hipStream_t stream) {
  const float* in = (const float*)d_in[0];
  float* out = (float*)d_out;
  int B = in_sizes[0] / 24;
  int blocks = (B + TPB - 1) / TPB;
  speaker_kernel<<<blocks, TPB, 0, stream>>>(in, out, B);
}